// Round 13
// baseline (177.576 us; speedup 1.0000x reference)
//
#include <hip/hip_runtime.h>

#define B 8
#define N 25200
#define ROW 85
#define NC 80
#define K 2048
#define MAXDET 300
#define NBUCKET 4096
#define CAND_CAP 4096
#define NCHUNK 32   /* K/64 */
#define STILE 64    /* score tile rows */

// ---------------------------------------------------------------------------
// Kernel 1: score/cls per box + xyxy boxes4 (bit-identical box math).
// ---------------------------------------------------------------------------
__global__ void __launch_bounds__(256)
nms_score_kernel(const float* __restrict__ x,
                 float* __restrict__ scores,
                 int* __restrict__ cls_id,
                 float4* __restrict__ boxes4) {
    int b = blockIdx.y;
    int i0 = blockIdx.x * STILE;
    int rows = N - i0; if (rows > STILE) rows = STILE;
    __shared__ float lx[STILE * ROW];   // 21760 B
    {
        const float4* s4 = (const float4*)(x + ((size_t)b * N + i0) * ROW);
        float4* d4 = (float4*)lx;
        int nv = rows * ROW / 4;        // 1360 or 1020 (both exact)
        for (int k = threadIdx.x; k < nv; k += 256) d4[k] = s4[k];
    }
    __syncthreads();
    int g = threadIdx.x >> 2;          // box in tile
    int q = threadIdx.x & 3;
    if (g >= rows) return;             // uniform across the 4-lane group
    const float* p = lx + g * ROW;
    float obj = p[4];
    float best = -1e30f;
    int bc = 127;
    if (obj > 0.3f) {
        #pragma unroll
        for (int k = 0; k < 20; ++k) {
            int c = q + 4 * k;
            float v = __fmul_rn(p[5 + c], obj);   // exact, no FMA
            if (v > best) { best = v; bc = c; }   // strict >: in-lane first-max
        }
    }
    #pragma unroll
    for (int m = 1; m < 4; m <<= 1) {   // combine: higher v, tie -> smaller class
        float ov = __shfl_xor(best, m, 64);
        int   oc = __shfl_xor(bc, m, 64);
        if (ov > best || (ov == best && oc < bc)) { best = ov; bc = oc; }
    }
    if (q == 0) {
        int i = i0 + g;
        float score = (obj > 0.3f && best > 0.3f) ? best : -1.0f;
        scores[b * N + i] = score;
        cls_id[b * N + i] = (bc == 127) ? 0 : bc;
        float cx = p[0], cy = p[1], w = p[2], h = p[3];
        float hx = __fmul_rn(w, 0.5f);
        float hy = __fmul_rn(h, 0.5f);
        boxes4[b * N + i] = make_float4(__fsub_rn(cx, hx), __fsub_rn(cy, hy),
                                        __fadd_rn(cx, hx), __fadd_rn(cy, hy));
    }
}

// ---------------------------------------------------------------------------
// Kernel 2 (tail): 8 blocks x 1024 threads, one block per batch, zero
// cross-block sync. R13 changes vs R12 (both chains were measured hogs):
//  * per-bucket insertion sort -> exact-rank scatter (independent LDS reads;
//    rank = bucket start + #{same-bucket stored keys > mine}; unique keys =>
//    bit-identical sorted keys[0..K)).
//  * NMS greedy ballot-chain -> precomputed suppression rows (independent
//    build, exact fp op order) + pipelined shfl scan over keepw.
// Flat LDS (93 KB), no union aliasing.
// ---------------------------------------------------------------------------
__global__ void __launch_bounds__(1024, 1)
nms_tail_kernel(const float* __restrict__ scores,
                const float4* __restrict__ boxes4,
                const int* __restrict__ cls_id,
                float* __restrict__ out) {
    __shared__ struct {
        unsigned loff[NBUCKET];              // 16 KB hist -> start ranks
        unsigned lcnt16[NBUCKET / 2];        // 8 KB packed u16 cursors
        unsigned long long lk[CAND_CAP];     // 32 KB placement slots
        unsigned long long keys[K];          // 16 KB final sorted keys
        unsigned long long lcm[NC * NCHUNK]; // 20 KB class masks
        unsigned long long lkeep[NCHUNK];    // kept bits
        unsigned long long kept[NCHUNK];     // output: kept words
        unsigned kcpref[NCHUNK];             // output: kept prefix
        int total;                           // output: total kept
    } U;                                     // ~93 KB
    __shared__ unsigned wsum[16];

    int b = blockIdx.x;
    int t = threadIdx.x;
    int ln = t & 63, wv = t >> 6;
    unsigned long long below = (ln == 0) ? 0ULL : (~0ULL >> (64 - ln));
    constexpr int NITER = (N + 1023) / 1024;    // 25

    // ================= zero everything upfront =================
    {
        uint4 z = {0u, 0u, 0u, 0u};
        uint4* d1 = (uint4*)U.loff;
        for (int k = t; k < (NBUCKET + NBUCKET / 2) / 4; k += 1024) d1[k] = z;
    }
    for (int k = t; k < CAND_CAP; k += 1024) U.lk[k] = 0ULL;
    for (int k = t; k < K; k += 1024) U.keys[k] = 0ULL;
    for (int k = t; k < NC * NCHUNK; k += 1024) U.lcm[k] = 0ULL;
    if (t < NCHUNK) U.lkeep[t] = 0ULL;
    __syncthreads();

    // ================= histogram pass (scores cached in registers) ========
    float sreg[NITER];
    #pragma unroll
    for (int r = 0; r < NITER; ++r) {
        int i = t + r * 1024;
        float s = (i < N) ? scores[b * N + i] : -1.0f;
        sreg[r] = s;
        if (s > 0.0f) {
            int q = (int)(__fmul_rn(s, 4096.0f));
            if (q > NBUCKET - 1) q = NBUCKET - 1;
            atomicAdd(&U.loff[q], 1u);
        }
    }
    __syncthreads();

    // ================= descending exclusive scan in place =================
    // thread t owns buckets 4095-4t .. 4092-4t (uint4 index 1023-t).
    {
        unsigned v[4];
        unsigned A4 = (unsigned)(NBUCKET / 4 - 1 - t);
        {
            uint4 u0 = ((uint4*)U.loff)[A4];
            v[0] = u0.w; v[1] = u0.z; v[2] = u0.y; v[3] = u0.x;
        }
        unsigned S = v[0] + v[1] + v[2] + v[3];
        unsigned pref = S;
        #pragma unroll
        for (int o = 1; o < 64; o <<= 1) { unsigned u = __shfl_up(pref, o, 64); if (ln >= o) pref += u; }
        if (ln == 63) wsum[wv] = pref;
        __syncthreads();
        unsigned wbase = 0;
        for (int w = 0; w < wv; ++w) wbase += wsum[w];
        unsigned running = wbase + pref - S;
        unsigned o[4];
        #pragma unroll
        for (int k = 0; k < 4; ++k) { o[3 - k] = running; running += v[k]; }
        ((uint4*)U.loff)[A4] = make_uint4(o[0], o[1], o[2], o[3]);
    }
    __syncthreads();

    // ================= placement (counting sort) =================
    #pragma unroll
    for (int r = 0; r < NITER; ++r) {
        float s = sreg[r];
        if (s > 0.0f) {
            int i = t + r * 1024;
            int q = (int)(__fmul_rn(s, 4096.0f));
            if (q > NBUCKET - 1) q = NBUCKET - 1;
            unsigned start = U.loff[q];
            if (start < CAND_CAP) {
                unsigned sh = (q & 1) * 16;
                unsigned old = atomicAdd(&U.lcnt16[q >> 1], 1u << sh);
                unsigned rank = (old >> sh) & 0xFFFFu;
                unsigned pos = start + rank;
                if (pos < CAND_CAP) {
                    unsigned long long key =
                        ((unsigned long long)__float_as_uint(s) << 32) | (unsigned)(~i);
                    U.lk[pos] = key;
                }
            }
        }
    }
    __syncthreads();

    // ================= exact-rank scatter (replaces insertion sort) =======
    // rank(elem) = bucket start + #{stored same-bucket keys > mine}.
    // Unique keys + identical comparator => bit-identical sorted keys[0..K).
    for (int p = t; p < CAND_CAP; p += 1024) {
        unsigned long long key = U.lk[p];
        if (key != 0ULL) {
            float s = __uint_as_float((unsigned)(key >> 32));
            int q = (int)(__fmul_rn(s, 4096.0f));
            if (q > NBUCKET - 1) q = NBUCKET - 1;
            unsigned start = U.loff[q];
            unsigned cnt = (U.lcnt16[q >> 1] >> ((q & 1) * 16)) & 0xFFFFu;
            unsigned m = cnt;
            if (m > CAND_CAP - start) m = CAND_CAP - start;
            unsigned rank = start;
            for (unsigned a = start; a < start + m; ++a)
                rank += (U.lk[a] > key) ? 1u : 0u;   // independent LDS reads
            if (rank < K) U.keys[rank] = key;
        }
    }
    __syncthreads();

    // ================= class-mask build =================
    for (int r = t; r < K; r += 1024) {
        unsigned long long key = U.keys[r];
        if (key != 0ULL) {
            int idx = (int)(~(unsigned)key);
            int cc = cls_id[b * N + idx];
            atomicOr(&U.lcm[cc * NCHUNK + (r >> 6)], 1ULL << (r & 63));
        }
    }
    __syncthreads();

    // ================= per-wave class NMS: 5 rounds =================
    for (int round = 0; round < 5; ++round) {
        int c = round * 16 + wv;     // this wave's class this round, 0..79

        // register compaction: lane ln -> ln-th member (rank-ascending)
        int n = 0, r = -1, ch_i = -1, myk = -1;
        unsigned long long mych = 0ULL;
        for (int ch = 0; ch < NCHUNK; ++ch) {
            unsigned long long m = U.lcm[c * NCHUNK + ch];   // wave-uniform
            int cnt = __popcll(m);
            if (myk < 0 && ln < n + cnt) { mych = m; myk = ln - n; ch_i = ch; }
            n += cnt;
        }
        if (myk >= 0) {
            unsigned long long mm = mych;
            for (int z = 0; z < myk; ++z) mm &= mm - 1;
            r = ch_i * 64 + (int)__builtin_ctzll(mm);
        }

        float shf = __fmul_rn((float)c, 4096.0f);   // class shift (uniform)

        if (n > 0 && n <= 64) {
            // member ln computes its shifted box in-lane from boxes4
            float x1 = 0.f, y1 = 0.f, x2 = 0.f, y2 = 0.f, ar = 0.f;
            if (ln < n) {
                unsigned long long key = U.keys[r];
                int idx = (int)(~(unsigned)key);
                float4 bb = boxes4[(size_t)b * N + idx];
                x1 = __fadd_rn(bb.x, shf); y1 = __fadd_rn(bb.y, shf);
                x2 = __fadd_rn(bb.z, shf); y2 = __fadd_rn(bb.w, shf);
                ar = __fmul_rn(__fsub_rn(x2, x1), __fsub_rn(y2, y1));
            }
            // build suppression rows: bit j of rows = (j>ln) && iou(ln,j)>0.6
            // (independent across j: all shfl broadcasts pipeline; cond never
            //  depended on keepw in the old chain => exactly equivalent)
            unsigned long long rows_ = 0ULL;
            for (int j = 0; j < n; ++j) {
                float jx1 = __shfl(x1, j, 64), jy1 = __shfl(y1, j, 64);
                float jx2 = __shfl(x2, j, 64), jy2 = __shfl(y2, j, 64);
                float jar = __shfl(ar, j, 64);
                bool cond = false;
                if (ln < n && j > ln) {
                    // lane = i (suppressor), broadcast = j (candidate);
                    // operand order mirrors the old (i-broadcast) code exactly
                    float lx = fmaxf(x1, jx1), ly = fmaxf(y1, jy1);
                    float rx = fminf(x2, jx2), ry = fminf(y2, jy2);
                    float w = fmaxf(__fsub_rn(rx, lx), 0.0f);
                    float h = fmaxf(__fsub_rn(ry, ly), 0.0f);
                    float inter = __fmul_rn(w, h);
                    float denom = __fadd_rn(__fsub_rn(__fadd_rn(ar, jar), inter), 1e-9f);
                    cond = __fdiv_rn(inter, denom) > 0.6f;   // exact ref order
                }
                if (cond) rows_ |= 1ULL << j;
            }
            // greedy scan: shfls independent of keepw -> pipelined
            unsigned long long keepw = (n == 64) ? ~0ULL : ((1ULL << n) - 1ULL);
            for (int i = 0; i < n; ++i) {
                unsigned long long ri = __shfl(rows_, i, 64);
                if ((keepw >> i) & 1ULL) keepw &= ~ri;
            }
            if (ln < n && ((keepw >> ln) & 1ULL))
                atomicOr(&U.lkeep[r >> 6], 1ULL << (r & 63));   // LDS
        } else if (n > 64) {
            // general path (n > 64): wave-local register-distributed keep
            // bits. Correctness-only; unreachable for this data distribution.
            unsigned long long membw = (ln < NCHUNK) ? U.lcm[c * NCHUNK + ln] : 0ULL;
            unsigned long long keepw2 = membw;
            for (int i = 0; i < K; ++i) {
                int ch = i >> 6;
                unsigned long long mw = __shfl(membw, ch, 64);
                unsigned long long kw = __shfl(keepw2, ch, 64);
                unsigned long long bi = 1ULL << (i & 63);
                if (!(mw & kw & bi)) continue;   // uniform
                unsigned long long keyi = U.keys[i];               // uniform
                int idxi = (int)(~(unsigned)keyi);
                float4 bi4 = boxes4[(size_t)b * N + idxi];
                float bx1 = __fadd_rn(bi4.x, shf), by1 = __fadd_rn(bi4.y, shf);
                float bx2 = __fadd_rn(bi4.z, shf), by2 = __fadd_rn(bi4.w, shf);
                float ba = __fmul_rn(__fsub_rn(bx2, bx1), __fsub_rn(by2, by1));
                for (int c2 = ch; c2 < NCHUNK; ++c2) {
                    int j = c2 * 64 + ln;
                    unsigned long long mw2 = __shfl(membw, c2, 64);
                    bool cond = false;
                    if (j > i && ((mw2 >> ln) & 1ULL)) {
                        unsigned long long keyj = U.keys[j];
                        int idxj = (int)(~(unsigned)keyj);
                        float4 bj4 = boxes4[(size_t)b * N + idxj];
                        float x1 = __fadd_rn(bj4.x, shf), y1 = __fadd_rn(bj4.y, shf);
                        float x2 = __fadd_rn(bj4.z, shf), y2 = __fadd_rn(bj4.w, shf);
                        float arj = __fmul_rn(__fsub_rn(x2, x1), __fsub_rn(y2, y1));
                        float lx = fmaxf(bx1, x1), ly = fmaxf(by1, y1);
                        float rx = fminf(bx2, x2), ry = fminf(by2, y2);
                        float w = fmaxf(__fsub_rn(rx, lx), 0.0f);
                        float h = fmaxf(__fsub_rn(ry, ly), 0.0f);
                        float inter = __fmul_rn(w, h);
                        float denom = __fadd_rn(__fsub_rn(__fadd_rn(ba, arj), inter), 1e-9f);
                        cond = __fdiv_rn(inter, denom) > 0.6f;
                    }
                    unsigned long long sup = __ballot(cond);
                    if (ln == c2) keepw2 &= ~sup;
                }
            }
            unsigned long long kb = keepw2 & membw;
            if (ln < NCHUNK && kb)
                atomicOr(&U.lkeep[ln], kb);   // LDS
        }
    }
    __syncthreads();

    // ================= output phase (whole block) =================
    if (wv == 0) {
        unsigned long long kwv = (ln < NCHUNK) ? U.lkeep[ln] : 0ULL;
        unsigned pc = (unsigned)__popcll(kwv);
        unsigned incl = pc;
        #pragma unroll
        for (int o = 1; o < 32; o <<= 1) { unsigned u = __shfl_up(incl, o, 64); if (ln >= o) incl += u; }
        if (ln < NCHUNK) {
            U.kept[ln] = kwv;
            U.kcpref[ln] = incl - pc;      // exclusive kept prefix
        }
        if (ln == 31) U.total = (int)incl; // total kept
    }
    __syncthreads();

    {
        int total = U.total;
        float* dets  = out + (size_t)b * MAXDET * 6;
        float* flags = out + (size_t)B * MAXDET * 6 + (size_t)b * MAXDET;
        #pragma unroll
        for (int h = 0; h < 2; ++h) {
            int ch = wv * 2 + h;
            int i = ch * 64 + ln;
            unsigned long long m = U.kept[ch];
            bool k = ((m >> ln) & 1ULL) != 0ULL;
            int kp = (int)U.kcpref[ch];
            int np = ch * 64 - kp;           // exclusive non-kept prefix
            int slot = k ? (kp + (int)__popcll(m & below))
                         : (total + np + (int)__popcll((~m) & below));
            if (slot < MAXDET) {
                unsigned long long key = U.keys[i];
                float s, ox1, oy1, ox2, oy2; int oc;
                if (key == 0ULL) {
                    s = -1.0f; ox1 = oy1 = ox2 = oy2 = 0.0f; oc = 0;
                } else {
                    s = __uint_as_float((unsigned)(key >> 32));
                    int idx = (int)(~(unsigned)key);
                    float4 bb = boxes4[(size_t)b * N + idx];
                    ox1 = bb.x; oy1 = bb.y; ox2 = bb.z; oy2 = bb.w;
                    oc = cls_id[b * N + idx];
                }
                dets[slot * 6 + 0] = ox1;
                dets[slot * 6 + 1] = oy1;
                dets[slot * 6 + 2] = ox2;
                dets[slot * 6 + 3] = oy2;
                dets[slot * 6 + 4] = s;
                dets[slot * 6 + 5] = (float)oc;
                flags[slot] = k ? 1.0f : 0.0f;
            }
        }
    }
}

// ---------------------------------------------------------------------------
extern "C" void kernel_launch(void* const* d_in, const int* in_sizes, int n_in,
                              void* d_out, int out_size, void* d_ws, size_t ws_size,
                              hipStream_t stream) {
    const float* x = (const float*)d_in[0];
    float* out = (float*)d_out;

    char* ws = (char*)d_ws;
    size_t off = 0;
    auto alloc = [&](size_t bytes) -> void* {
        void* p = ws + off;
        off += bytes;
        off = (off + 255) & ~(size_t)255;
        return p;
    };

    float*  scores = (float*)  alloc((size_t)B * N * 4);
    int*    cls_id = (int*)    alloc((size_t)B * N * 4);
    float4* boxes4 = (float4*) alloc((size_t)B * N * 16);
    (void)ws_size; // needs ~2.4 MB

    nms_score_kernel<<<dim3((N + STILE - 1) / STILE, B), 256, 0, stream>>>(
        x, scores, cls_id, boxes4);
    nms_tail_kernel<<<B, 1024, 0, stream>>>(scores, boxes4, cls_id, out);
}

// Round 14
// 136.441 us; speedup vs baseline: 1.3015x; 1.3015x over previous
//
#include <hip/hip_runtime.h>

#define B 8
#define N 25200
#define ROW 85
#define NC 80
#define K 2048
#define MAXDET 300
#define NBUCKET 4096
#define CAND_CAP 4096
#define NCHUNK 32   /* K/64 */
#define STILE 64    /* score tile rows */
#define CTR_STRIDE 64   /* u32 stride per batch counter: 256B, no false sharing */

// ---------------------------------------------------------------------------
// Kernel 1: score/cls per box + xyxy boxes4 (bit-identical box math).
// Block (0,b) also zeroes done counter and keepbits for kernel 2.
// ---------------------------------------------------------------------------
__global__ void __launch_bounds__(256)
nms_score_kernel(const float* __restrict__ x,
                 float* __restrict__ scores,
                 int* __restrict__ cls_id,
                 float4* __restrict__ boxes4,
                 unsigned* __restrict__ done_ctr,
                 unsigned long long* __restrict__ keepbits) {
    int b = blockIdx.y;
    int i0 = blockIdx.x * STILE;
    if (blockIdx.x == 0) {
        if (threadIdx.x == 0) done_ctr[b * CTR_STRIDE] = 0u;
        if (threadIdx.x < NCHUNK) keepbits[b * NCHUNK + threadIdx.x] = 0ULL;
    }
    int rows = N - i0; if (rows > STILE) rows = STILE;
    __shared__ float lx[STILE * ROW];   // 21760 B
    {
        const float4* s4 = (const float4*)(x + ((size_t)b * N + i0) * ROW);
        float4* d4 = (float4*)lx;
        int nv = rows * ROW / 4;        // 1360 or 1020 (both exact)
        for (int k = threadIdx.x; k < nv; k += 256) d4[k] = s4[k];
    }
    __syncthreads();
    int g = threadIdx.x >> 2;          // box in tile
    int q = threadIdx.x & 3;
    if (g >= rows) return;             // uniform across the 4-lane group
    const float* p = lx + g * ROW;
    float obj = p[4];
    float best = -1e30f;
    int bc = 127;
    if (obj > 0.3f) {
        #pragma unroll
        for (int k = 0; k < 20; ++k) {
            int c = q + 4 * k;
            float v = __fmul_rn(p[5 + c], obj);   // exact, no FMA
            if (v > best) { best = v; bc = c; }   // strict >: in-lane first-max
        }
    }
    #pragma unroll
    for (int m = 1; m < 4; m <<= 1) {   // combine: higher v, tie -> smaller class
        float ov = __shfl_xor(best, m, 64);
        int   oc = __shfl_xor(bc, m, 64);
        if (ov > best || (ov == best && oc < bc)) { best = ov; bc = oc; }
    }
    if (q == 0) {
        int i = i0 + g;
        float score = (obj > 0.3f && best > 0.3f) ? best : -1.0f;
        scores[b * N + i] = score;
        cls_id[b * N + i] = (bc == 127) ? 0 : bc;
        float cx = p[0], cy = p[1], w = p[2], h = p[3];
        float hx = __fmul_rn(w, 0.5f);
        float hy = __fmul_rn(h, 0.5f);
        boxes4[b * N + i] = make_float4(__fsub_rn(cx, hx), __fsub_rn(cy, hy),
                                        __fadd_rn(cx, hx), __fadd_rn(cy, hy));
    }
}

// ---------------------------------------------------------------------------
// Kernel 2 (tail): 40 blocks x 1024 threads (R10 chassis, best measured).
// Block bid handles batch bid/5, classes (bid%5)*16 + wv — one NMS round.
// Each block replicates the full top-K select in LDS (parallel CUs make
// duplication free). R14 change vs R10: the round's row-build uses per-wave
// LDS-staged boxes (broadcast b128 reads) instead of 5 shfls per pair,
// cutting per-round wave-wide LDS-pipe ops ~2.2x (the measured W=9.7us/round
// is LDS-pipe throughput: 16 waves x ~190 ops share one LDS unit per CU).
// Key construction, sort, compaction, IoU fp sequence, finisher protocol,
// and output logic byte-identical to the R10/R13-verified lineage.
// ---------------------------------------------------------------------------
__global__ void __launch_bounds__(1024, 1)
nms_tail_kernel(const float* __restrict__ scores,
                const float4* __restrict__ boxes4,
                const int* __restrict__ cls_id,
                unsigned long long* __restrict__ keepbits,
                unsigned* __restrict__ done_ctr,
                float* __restrict__ out) {
    __shared__ union {
        struct {   // SELECT phase: 56 KB
            unsigned loff[NBUCKET];              // 16 KB hist -> start ranks
            unsigned lcnt16[NBUCKET / 2];        // 8 KB packed u16 cursors
            unsigned long long lk[CAND_CAP];     // 32 KB sort keys @ byte 24K
        } s;
        struct {   // NMS phase: ~54 KB
            unsigned long long keys[K];          // 16 KB sorted keys @ byte 0
            unsigned long long lcm[NC * NCHUNK]; // 20 KB class masks @ 16K
            float4 wbox[16][64];                 // 16 KB per-wave staged boxes
            unsigned long long kept[NCHUNK];     // finisher: kept words
            unsigned kcpref[NCHUNK];             // finisher: kept prefix
            int total;                           // finisher: total kept
            int oflag;                           // finisher-block flag
        } c;
    } U;
    __shared__ unsigned wsum[16];

    int bid = blockIdx.x;
    int t = threadIdx.x;
    int ln = t & 63, wv = t >> 6;
    unsigned long long below = (ln == 0) ? 0ULL : (~0ULL >> (64 - ln));

    int b = bid / 5;
    int grp = bid % 5;
    int c = grp * 16 + wv;      // this wave's class, 0..79
    constexpr int NITER = (N + 1023) / 1024;    // 25

    // ================= SELECT phase (replicated per block) =================
    {   // zero histogram + cursors (24 KB)
        uint4 z = {0u, 0u, 0u, 0u};
        uint4* d1 = (uint4*)U.s.loff;
        for (int k = t; k < (NBUCKET + NBUCKET / 2) / 4; k += 1024) d1[k] = z;
    }
    for (int k = t; k < CAND_CAP; k += 1024) U.s.lk[k] = 0ULL;
    __syncthreads();

    // histogram pass: single global read, cache scores in registers
    float sreg[NITER];
    #pragma unroll
    for (int r = 0; r < NITER; ++r) {
        int i = t + r * 1024;
        float s = (i < N) ? scores[b * N + i] : -1.0f;
        sreg[r] = s;
        if (s > 0.0f) {
            int q = (int)(__fmul_rn(s, 4096.0f));
            if (q > NBUCKET - 1) q = NBUCKET - 1;
            atomicAdd(&U.s.loff[q], 1u);
        }
    }
    __syncthreads();

    // descending exclusive scan in place: loff[q] = count in buckets > q.
    // thread t owns buckets 4095-4t .. 4092-4t (uint4 index 1023-t).
    {
        unsigned v[4];
        unsigned A4 = (unsigned)(NBUCKET / 4 - 1 - t);
        {
            uint4 u0 = ((uint4*)U.s.loff)[A4];
            v[0] = u0.w; v[1] = u0.z; v[2] = u0.y; v[3] = u0.x;
        }
        unsigned S = v[0] + v[1] + v[2] + v[3];
        unsigned pref = S;
        #pragma unroll
        for (int o = 1; o < 64; o <<= 1) { unsigned u = __shfl_up(pref, o, 64); if (ln >= o) pref += u; }
        if (ln == 63) wsum[wv] = pref;
        __syncthreads();
        unsigned wbase = 0;
        for (int w = 0; w < wv; ++w) wbase += wsum[w];
        unsigned running = wbase + pref - S;
        unsigned o[4];
        #pragma unroll
        for (int k = 0; k < 4; ++k) { o[3 - k] = running; running += v[k]; }
        ((uint4*)U.s.loff)[A4] = make_uint4(o[0], o[1], o[2], o[3]);
    }
    __syncthreads();

    // placement (counting sort) from register-cached scores
    #pragma unroll
    for (int r = 0; r < NITER; ++r) {
        float s = sreg[r];
        if (s > 0.0f) {
            int i = t + r * 1024;
            int q = (int)(__fmul_rn(s, 4096.0f));
            if (q > NBUCKET - 1) q = NBUCKET - 1;
            unsigned start = U.s.loff[q];
            if (start < CAND_CAP) {
                unsigned sh = (q & 1) * 16;
                unsigned old = atomicAdd(&U.s.lcnt16[q >> 1], 1u << sh);
                unsigned rank = (old >> sh) & 0xFFFFu;
                unsigned pos = start + rank;
                if (pos < CAND_CAP) {
                    unsigned long long key =
                        ((unsigned long long)__float_as_uint(s) << 32) | (unsigned)(~i);
                    U.s.lk[pos] = key;
                }
            }
        }
    }
    __syncthreads();

    // per-bucket insertion sort (descending keys), disjoint ranges
    for (int q = t; q < NBUCKET; q += 1024) {
        unsigned start = U.s.loff[q];
        if (start < CAND_CAP) {
            unsigned cc = (U.s.lcnt16[q >> 1] >> ((q & 1) * 16)) & 0xFFFFu;
            unsigned m = cc;
            if (m > CAND_CAP - start) m = CAND_CAP - start;
            if (m >= 2) {
                for (unsigned a = start + 1; a < start + m; ++a) {
                    unsigned long long kv = U.s.lk[a];
                    unsigned p2 = a;
                    while (p2 > start && U.s.lk[p2 - 1] < kv) { U.s.lk[p2] = U.s.lk[p2 - 1]; --p2; }
                    U.s.lk[p2] = kv;
                }
            }
        }
    }
    __syncthreads();

    // ================= transition: keys <- lk (disjoint LDS regions) =======
    // keys @ bytes [0,16K) ; lk @ bytes [24K,56K) -> safe concurrent copy.
    for (int r = t; r < K; r += 1024) U.c.keys[r] = U.s.lk[r];
    __syncthreads();
    // lcm overlaps dead lcnt16/lk only after the copy barrier.
    for (int k = t; k < NC * NCHUNK; k += 1024) U.c.lcm[k] = 0ULL;
    if (t == 0) U.c.oflag = 0;
    __syncthreads();

    // parallel class-mask build (1024 threads x 2 ranks)
    for (int r = t; r < K; r += 1024) {
        unsigned long long key = U.c.keys[r];
        if (key != 0ULL) {
            int idx = (int)(~(unsigned)key);
            int cc = cls_id[b * N + idx];
            atomicOr(&U.c.lcm[cc * NCHUNK + (r >> 6)], 1ULL << (r & 63));
        }
    }
    __syncthreads();

    // ================= per-wave class NMS (one round) =================
    // register compaction from LDS masks: lane ln -> ln-th member of class c
    int n = 0, r = -1, ch_i = -1, myk = -1;
    unsigned long long mych = 0ULL;
    for (int ch = 0; ch < NCHUNK; ++ch) {
        unsigned long long m = U.c.lcm[c * NCHUNK + ch];   // LDS, wave-uniform
        int cnt = __popcll(m);
        if (myk < 0 && ln < n + cnt) { mych = m; myk = ln - n; ch_i = ch; }
        n += cnt;
    }
    if (myk >= 0) {
        unsigned long long mm = mych;
        for (int z = 0; z < myk; ++z) mm &= mm - 1;
        r = ch_i * 64 + (int)__builtin_ctzll(mm);
    }

    float shf = __fmul_rn((float)c, 4096.0f);   // class shift (uniform)

    if (n > 0 && n <= 64) {
        // fast path: member ln computes its shifted box in-lane from boxes4,
        // stages it to the per-wave LDS array (one ds_write).
        float x1 = 0.f, y1 = 0.f, x2 = 0.f, y2 = 0.f, ar = 0.f;
        if (ln < n) {
            unsigned long long key = U.c.keys[r];
            int idx = (int)(~(unsigned)key);
            float4 bb = boxes4[(size_t)b * N + idx];
            x1 = __fadd_rn(bb.x, shf); y1 = __fadd_rn(bb.y, shf);
            x2 = __fadd_rn(bb.z, shf); y2 = __fadd_rn(bb.w, shf);
            ar = __fmul_rn(__fsub_rn(x2, x1), __fsub_rn(y2, y1));
            U.c.wbox[wv][ln] = make_float4(x1, y1, x2, y2);
        }
        // row build: lane ln = suppressor i; box_j via broadcast LDS read
        // (j-area recomputed with the identical op sequence -> bit-identical).
        unsigned long long rows_ = 0ULL;
        for (int j = 0; j < n; ++j) {
            float4 jb = U.c.wbox[wv][j];         // wave-uniform broadcast
            bool cond = false;
            if (ln < n && j > ln) {
                float jar = __fmul_rn(__fsub_rn(jb.z, jb.x), __fsub_rn(jb.w, jb.y));
                float lx = fmaxf(x1, jb.x), ly = fmaxf(y1, jb.y);
                float rx = fminf(x2, jb.z), ry = fminf(y2, jb.w);
                float w = fmaxf(__fsub_rn(rx, lx), 0.0f);
                float h = fmaxf(__fsub_rn(ry, ly), 0.0f);
                float inter = __fmul_rn(w, h);
                float denom = __fadd_rn(__fsub_rn(__fadd_rn(ar, jar), inter), 1e-9f);
                cond = __fdiv_rn(inter, denom) > 0.6f;   // exact ref order
            }
            if (cond) rows_ |= 1ULL << j;
        }
        // greedy scan (R13-verified): shfls independent of keepw -> pipelined
        unsigned long long keepw = (n == 64) ? ~0ULL : ((1ULL << n) - 1ULL);
        for (int i = 0; i < n; ++i) {
            unsigned long long ri = __shfl(rows_, i, 64);
            if ((keepw >> i) & 1ULL) keepw &= ~ri;
        }
        if (ln < n && ((keepw >> ln) & 1ULL))
            atomicOr(&keepbits[b * NCHUNK + (r >> 6)], 1ULL << (r & 63));
    } else if (n > 64) {
        // general path (n > 64): wave-local register-distributed keep bits.
        // Correctness-only; unreachable for this data distribution.
        unsigned long long membw = (ln < NCHUNK) ? U.c.lcm[c * NCHUNK + ln] : 0ULL;
        unsigned long long keepw2 = membw;
        for (int i = 0; i < K; ++i) {
            int ch = i >> 6;
            unsigned long long mw = __shfl(membw, ch, 64);
            unsigned long long kw = __shfl(keepw2, ch, 64);
            unsigned long long bi = 1ULL << (i & 63);
            if (!(mw & kw & bi)) continue;   // uniform (shfl results uniform)
            unsigned long long keyi = U.c.keys[i];             // uniform
            int idxi = (int)(~(unsigned)keyi);
            float4 bi4 = boxes4[(size_t)b * N + idxi];
            float bx1 = __fadd_rn(bi4.x, shf), by1 = __fadd_rn(bi4.y, shf);
            float bx2 = __fadd_rn(bi4.z, shf), by2 = __fadd_rn(bi4.w, shf);
            float ba = __fmul_rn(__fsub_rn(bx2, bx1), __fsub_rn(by2, by1));
            for (int c2 = ch; c2 < NCHUNK; ++c2) {
                int j = c2 * 64 + ln;
                unsigned long long mw2 = __shfl(membw, c2, 64);
                bool cond = false;
                if (j > i && ((mw2 >> ln) & 1ULL)) {
                    unsigned long long keyj = U.c.keys[j];
                    int idxj = (int)(~(unsigned)keyj);
                    float4 bj4 = boxes4[(size_t)b * N + idxj];
                    float x1 = __fadd_rn(bj4.x, shf), y1 = __fadd_rn(bj4.y, shf);
                    float x2 = __fadd_rn(bj4.z, shf), y2 = __fadd_rn(bj4.w, shf);
                    float arj = __fmul_rn(__fsub_rn(x2, x1), __fsub_rn(y2, y1));
                    float lx = fmaxf(bx1, x1), ly = fmaxf(by1, y1);
                    float rx = fminf(bx2, x2), ry = fminf(by2, y2);
                    float w = fmaxf(__fsub_rn(rx, lx), 0.0f);
                    float h = fmaxf(__fsub_rn(ry, ly), 0.0f);
                    float inter = __fmul_rn(w, h);
                    float denom = __fadd_rn(__fsub_rn(__fadd_rn(ba, arj), inter), 1e-9f);
                    cond = __fdiv_rn(inter, denom) > 0.6f;
                }
                unsigned long long sup = __ballot(cond);
                if (ln == c2) keepw2 &= ~sup;
            }
        }
        if (ln < NCHUNK && (keepw2 & membw))
            atomicOr(&keepbits[b * NCHUNK + ln], keepw2 & membw);
    }

    // ---- last-finisher detection + BLOCK-parallel output phase ----
    __threadfence();
    unsigned old = 0;
    if (ln == 0) old = atomicAdd(&done_ctr[b * CTR_STRIDE], 1u);
    old = (unsigned)__shfl((int)old, 0, 64);
    if (old == NC - 1) {
        // finisher wave: coherent kept read + per-chunk prefix into LDS
        __threadfence();
        unsigned long long kwv = 0ULL;
        if (ln < NCHUNK) kwv = atomicOr(&keepbits[b * NCHUNK + ln], 0ULL);
        unsigned pc = (unsigned)__popcll(kwv);
        unsigned incl = pc;
        #pragma unroll
        for (int o = 1; o < 32; o <<= 1) { unsigned u = __shfl_up(incl, o, 64); if (ln >= o) incl += u; }
        if (ln < NCHUNK) {
            U.c.kept[ln] = kwv;
            U.c.kcpref[ln] = incl - pc;      // exclusive kept prefix
        }
        if (ln == 31) U.c.total = (int)incl; // total kept
        if (ln == 0)  U.c.oflag = 1;
    }
    __syncthreads();

    if (U.c.oflag) {
        int total = U.c.total;
        float* dets  = out + (size_t)b * MAXDET * 6;
        float* flags = out + (size_t)B * MAXDET * 6 + (size_t)b * MAXDET;
        #pragma unroll
        for (int h = 0; h < 2; ++h) {
            int ch = wv * 2 + h;
            int i = ch * 64 + ln;
            unsigned long long m = U.c.kept[ch];
            bool k = ((m >> ln) & 1ULL) != 0ULL;
            int kp = (int)U.c.kcpref[ch];
            int np = ch * 64 - kp;           // exclusive non-kept prefix
            int slot = k ? (kp + (int)__popcll(m & below))
                         : (total + np + (int)__popcll((~m) & below));
            if (slot < MAXDET) {
                unsigned long long key = U.c.keys[i];
                float s, ox1, oy1, ox2, oy2; int oc;
                if (key == 0ULL) {
                    s = -1.0f; ox1 = oy1 = ox2 = oy2 = 0.0f; oc = 0;
                } else {
                    s = __uint_as_float((unsigned)(key >> 32));
                    int idx = (int)(~(unsigned)key);
                    float4 bb = boxes4[(size_t)b * N + idx];
                    ox1 = bb.x; oy1 = bb.y; ox2 = bb.z; oy2 = bb.w;
                    oc = cls_id[b * N + idx];
                }
                dets[slot * 6 + 0] = ox1;
                dets[slot * 6 + 1] = oy1;
                dets[slot * 6 + 2] = ox2;
                dets[slot * 6 + 3] = oy2;
                dets[slot * 6 + 4] = s;
                dets[slot * 6 + 5] = (float)oc;
                flags[slot] = k ? 1.0f : 0.0f;
            }
        }
    }
}

// ---------------------------------------------------------------------------
extern "C" void kernel_launch(void* const* d_in, const int* in_sizes, int n_in,
                              void* d_out, int out_size, void* d_ws, size_t ws_size,
                              hipStream_t stream) {
    const float* x = (const float*)d_in[0];
    float* out = (float*)d_out;

    char* ws = (char*)d_ws;
    size_t off = 0;
    auto alloc = [&](size_t bytes) -> void* {
        void* p = ws + off;
        off += bytes;
        off = (off + 255) & ~(size_t)255;
        return p;
    };

    float*    scores = (float*)    alloc((size_t)B * N * 4);
    int*      cls_id = (int*)      alloc((size_t)B * N * 4);
    float4*   boxes4 = (float4*)   alloc((size_t)B * N * 16);
    unsigned long long* keepbits = (unsigned long long*) alloc((size_t)B * NCHUNK * 8);
    unsigned* done_ctr = (unsigned*) alloc((size_t)B * CTR_STRIDE * 4);
    (void)ws_size; // needs ~2.6 MB

    nms_score_kernel<<<dim3((N + STILE - 1) / STILE, B), 256, 0, stream>>>(
        x, scores, cls_id, boxes4, done_ctr, keepbits);
    nms_tail_kernel<<<5 * B, 1024, 0, stream>>>(
        scores, boxes4, cls_id, keepbits, done_ctr, out);
}

// Round 16
// 132.726 us; speedup vs baseline: 1.3379x; 1.0280x over previous
//
#include <hip/hip_runtime.h>

#define B 8
#define N 25200
#define ROW 85
#define NC 80
#define K 2048
#define MAXDET 300
#define NBUCKET 4096
#define CAND_CAP 4096
#define NCHUNK 32   /* K/64 */
#define STILE 64    /* score tile rows */
#define CTR_STRIDE 64   /* u32 stride per batch counter: 256B, no false sharing */

// ---------------------------------------------------------------------------
// Kernel 1: score/cls per box + xyxy boxes4 (bit-identical box math).
// Block (0,b) also zeroes done counter and keepbits for kernel 2.
// ---------------------------------------------------------------------------
__global__ void __launch_bounds__(256)
nms_score_kernel(const float* __restrict__ x,
                 float* __restrict__ scores,
                 int* __restrict__ cls_id,
                 float4* __restrict__ boxes4,
                 unsigned* __restrict__ done_ctr,
                 unsigned long long* __restrict__ keepbits) {
    int b = blockIdx.y;
    int i0 = blockIdx.x * STILE;
    if (blockIdx.x == 0) {
        if (threadIdx.x == 0) done_ctr[b * CTR_STRIDE] = 0u;
        if (threadIdx.x < NCHUNK) keepbits[b * NCHUNK + threadIdx.x] = 0ULL;
    }
    int rows = N - i0; if (rows > STILE) rows = STILE;
    __shared__ float lx[STILE * ROW];   // 21760 B
    {
        const float4* s4 = (const float4*)(x + ((size_t)b * N + i0) * ROW);
        float4* d4 = (float4*)lx;
        int nv = rows * ROW / 4;        // 1360 or 1020 (both exact)
        for (int k = threadIdx.x; k < nv; k += 256) d4[k] = s4[k];
    }
    __syncthreads();
    int g = threadIdx.x >> 2;          // box in tile
    int q = threadIdx.x & 3;
    if (g >= rows) return;             // uniform across the 4-lane group
    const float* p = lx + g * ROW;
    float obj = p[4];
    float best = -1e30f;
    int bc = 127;
    if (obj > 0.3f) {
        #pragma unroll
        for (int k = 0; k < 20; ++k) {
            int c = q + 4 * k;
            float v = __fmul_rn(p[5 + c], obj);   // exact, no FMA
            if (v > best) { best = v; bc = c; }   // strict >: in-lane first-max
        }
    }
    #pragma unroll
    for (int m = 1; m < 4; m <<= 1) {   // combine: higher v, tie -> smaller class
        float ov = __shfl_xor(best, m, 64);
        int   oc = __shfl_xor(bc, m, 64);
        if (ov > best || (ov == best && oc < bc)) { best = ov; bc = oc; }
    }
    if (q == 0) {
        int i = i0 + g;
        float score = (obj > 0.3f && best > 0.3f) ? best : -1.0f;
        scores[b * N + i] = score;
        cls_id[b * N + i] = (bc == 127) ? 0 : bc;
        float cx = p[0], cy = p[1], w = p[2], h = p[3];
        float hx = __fmul_rn(w, 0.5f);
        float hy = __fmul_rn(h, 0.5f);
        boxes4[b * N + i] = make_float4(__fsub_rn(cx, hx), __fsub_rn(cy, hy),
                                        __fadd_rn(cx, hx), __fadd_rn(cy, hy));
    }
}

// ---------------------------------------------------------------------------
// Kernel 2 (tail): 40 blocks x 1024 threads (R10/R14 chassis, best measured).
// R15 change (single variable): the two N-passes over scores use float4
// loads (N = 4*6300 exactly; 7 vector loads/thread instead of 25 scalar) —
// per guide G13, scalar loads were the last unvectorized memory path and the
// suspected load-issue-serialization hog in the ~40us select core.
// Histogram adds commutative; placement arrival order was never canonical
// (unique-full-key insertion sort canonicalizes lk[0..K), straddling bucket
// lives above rank K) -> bit-identical keys. All else byte-identical R14.
// ---------------------------------------------------------------------------
__global__ void __launch_bounds__(1024, 1)
nms_tail_kernel(const float* __restrict__ scores,
                const float4* __restrict__ boxes4,
                const int* __restrict__ cls_id,
                unsigned long long* __restrict__ keepbits,
                unsigned* __restrict__ done_ctr,
                float* __restrict__ out) {
    __shared__ union {
        struct {   // SELECT phase: 56 KB
            unsigned loff[NBUCKET];              // 16 KB hist -> start ranks
            unsigned lcnt16[NBUCKET / 2];        // 8 KB packed u16 cursors
            unsigned long long lk[CAND_CAP];     // 32 KB sort keys @ byte 24K
        } s;
        struct {   // NMS phase: ~54 KB
            unsigned long long keys[K];          // 16 KB sorted keys @ byte 0
            unsigned long long lcm[NC * NCHUNK]; // 20 KB class masks @ 16K
            float4 wbox[16][64];                 // 16 KB per-wave staged boxes
            unsigned long long kept[NCHUNK];     // finisher: kept words
            unsigned kcpref[NCHUNK];             // finisher: kept prefix
            int total;                           // finisher: total kept
            int oflag;                           // finisher-block flag
        } c;
    } U;
    __shared__ unsigned wsum[16];

    int bid = blockIdx.x;
    int t = threadIdx.x;
    int ln = t & 63, wv = t >> 6;
    unsigned long long below = (ln == 0) ? 0ULL : (~0ULL >> (64 - ln));

    int b = bid / 5;
    int grp = bid % 5;
    int c = grp * 16 + wv;      // this wave's class, 0..79
    constexpr int NV4 = N / 4;                    // 6300, exact
    constexpr int NITER4 = (NV4 + 1023) / 1024;   // 7

    // ================= SELECT phase (replicated per block) =================
    {   // zero histogram + cursors (24 KB)
        uint4 z = {0u, 0u, 0u, 0u};
        uint4* d1 = (uint4*)U.s.loff;
        for (int k = t; k < (NBUCKET + NBUCKET / 2) / 4; k += 1024) d1[k] = z;
    }
    for (int k = t; k < CAND_CAP; k += 1024) U.s.lk[k] = 0ULL;
    __syncthreads();

    // histogram pass: float4 global reads, cached in registers
    const float4* sc4 = (const float4*)(scores + (size_t)b * N);
    float4 sreg4[NITER4];
    #pragma unroll
    for (int r = 0; r < NITER4; ++r) {
        int i4 = t + r * 1024;
        float4 v = (i4 < NV4) ? sc4[i4] : make_float4(-1.f, -1.f, -1.f, -1.f);
        sreg4[r] = v;
        float sv[4] = {v.x, v.y, v.z, v.w};
        #pragma unroll
        for (int k = 0; k < 4; ++k) {
            float s = sv[k];
            if (s > 0.0f) {
                int q = (int)(__fmul_rn(s, 4096.0f));
                if (q > NBUCKET - 1) q = NBUCKET - 1;
                atomicAdd(&U.s.loff[q], 1u);
            }
        }
    }
    __syncthreads();

    // descending exclusive scan in place: loff[q] = count in buckets > q.
    // thread t owns buckets 4095-4t .. 4092-4t (uint4 index 1023-t).
    {
        unsigned v[4];
        unsigned A4 = (unsigned)(NBUCKET / 4 - 1 - t);
        {
            uint4 u0 = ((uint4*)U.s.loff)[A4];
            v[0] = u0.w; v[1] = u0.z; v[2] = u0.y; v[3] = u0.x;
        }
        unsigned S = v[0] + v[1] + v[2] + v[3];
        unsigned pref = S;
        #pragma unroll
        for (int o = 1; o < 64; o <<= 1) { unsigned u = __shfl_up(pref, o, 64); if (ln >= o) pref += u; }
        if (ln == 63) wsum[wv] = pref;
        __syncthreads();
        unsigned wbase = 0;
        for (int w = 0; w < wv; ++w) wbase += wsum[w];
        unsigned running = wbase + pref - S;
        unsigned o[4];
        #pragma unroll
        for (int k = 0; k < 4; ++k) { o[3 - k] = running; running += v[k]; }
        ((uint4*)U.s.loff)[A4] = make_uint4(o[0], o[1], o[2], o[3]);
    }
    __syncthreads();

    // placement (counting sort) from register-cached scores
    #pragma unroll
    for (int r = 0; r < NITER4; ++r) {
        int i4 = t + r * 1024;
        float4 v = sreg4[r];
        float sv[4] = {v.x, v.y, v.z, v.w};
        #pragma unroll
        for (int k = 0; k < 4; ++k) {
            float s = sv[k];
            if (s > 0.0f) {
                int i = i4 * 4 + k;
                int q = (int)(__fmul_rn(s, 4096.0f));
                if (q > NBUCKET - 1) q = NBUCKET - 1;
                unsigned start = U.s.loff[q];
                if (start < CAND_CAP) {
                    unsigned sh = (q & 1) * 16;
                    unsigned old = atomicAdd(&U.s.lcnt16[q >> 1], 1u << sh);
                    unsigned rank = (old >> sh) & 0xFFFFu;
                    unsigned pos = start + rank;
                    if (pos < CAND_CAP) {
                        unsigned long long key =
                            ((unsigned long long)__float_as_uint(s) << 32) | (unsigned)(~i);
                        U.s.lk[pos] = key;
                    }
                }
            }
        }
    }
    __syncthreads();

    // per-bucket insertion sort (descending keys), disjoint ranges
    for (int q = t; q < NBUCKET; q += 1024) {
        unsigned start = U.s.loff[q];
        if (start < CAND_CAP) {
            unsigned cc = (U.s.lcnt16[q >> 1] >> ((q & 1) * 16)) & 0xFFFFu;
            unsigned m = cc;
            if (m > CAND_CAP - start) m = CAND_CAP - start;
            if (m >= 2) {
                for (unsigned a = start + 1; a < start + m; ++a) {
                    unsigned long long kv = U.s.lk[a];
                    unsigned p2 = a;
                    while (p2 > start && U.s.lk[p2 - 1] < kv) { U.s.lk[p2] = U.s.lk[p2 - 1]; --p2; }
                    U.s.lk[p2] = kv;
                }
            }
        }
    }
    __syncthreads();

    // ================= transition: keys <- lk (disjoint LDS regions) =======
    // keys @ bytes [0,16K) ; lk @ bytes [24K,56K) -> safe concurrent copy.
    for (int r = t; r < K; r += 1024) U.c.keys[r] = U.s.lk[r];
    __syncthreads();
    // lcm overlaps dead lcnt16/lk only after the copy barrier.
    for (int k = t; k < NC * NCHUNK; k += 1024) U.c.lcm[k] = 0ULL;
    if (t == 0) U.c.oflag = 0;
    __syncthreads();

    // parallel class-mask build (1024 threads x 2 ranks)
    for (int r = t; r < K; r += 1024) {
        unsigned long long key = U.c.keys[r];
        if (key != 0ULL) {
            int idx = (int)(~(unsigned)key);
            int cc = cls_id[b * N + idx];
            atomicOr(&U.c.lcm[cc * NCHUNK + (r >> 6)], 1ULL << (r & 63));
        }
    }
    __syncthreads();

    // ================= per-wave class NMS (one round) =================
    // register compaction from LDS masks: lane ln -> ln-th member of class c
    int n = 0, r = -1, ch_i = -1, myk = -1;
    unsigned long long mych = 0ULL;
    for (int ch = 0; ch < NCHUNK; ++ch) {
        unsigned long long m = U.c.lcm[c * NCHUNK + ch];   // LDS, wave-uniform
        int cnt = __popcll(m);
        if (myk < 0 && ln < n + cnt) { mych = m; myk = ln - n; ch_i = ch; }
        n += cnt;
    }
    if (myk >= 0) {
        unsigned long long mm = mych;
        for (int z = 0; z < myk; ++z) mm &= mm - 1;
        r = ch_i * 64 + (int)__builtin_ctzll(mm);
    }

    float shf = __fmul_rn((float)c, 4096.0f);   // class shift (uniform)

    if (n > 0 && n <= 64) {
        // fast path: member ln computes its shifted box in-lane from boxes4,
        // stages it to the per-wave LDS array (one ds_write).
        float x1 = 0.f, y1 = 0.f, x2 = 0.f, y2 = 0.f, ar = 0.f;
        if (ln < n) {
            unsigned long long key = U.c.keys[r];
            int idx = (int)(~(unsigned)key);
            float4 bb = boxes4[(size_t)b * N + idx];
            x1 = __fadd_rn(bb.x, shf); y1 = __fadd_rn(bb.y, shf);
            x2 = __fadd_rn(bb.z, shf); y2 = __fadd_rn(bb.w, shf);
            ar = __fmul_rn(__fsub_rn(x2, x1), __fsub_rn(y2, y1));
            U.c.wbox[wv][ln] = make_float4(x1, y1, x2, y2);
        }
        // row build: lane ln = suppressor i; box_j via broadcast LDS read
        // (j-area recomputed with the identical op sequence -> bit-identical).
        unsigned long long rows_ = 0ULL;
        for (int j = 0; j < n; ++j) {
            float4 jb = U.c.wbox[wv][j];         // wave-uniform broadcast
            bool cond = false;
            if (ln < n && j > ln) {
                float jar = __fmul_rn(__fsub_rn(jb.z, jb.x), __fsub_rn(jb.w, jb.y));
                float lx = fmaxf(x1, jb.x), ly = fmaxf(y1, jb.y);
                float rx = fminf(x2, jb.z), ry = fminf(y2, jb.w);
                float w = fmaxf(__fsub_rn(rx, lx), 0.0f);
                float h = fmaxf(__fsub_rn(ry, ly), 0.0f);
                float inter = __fmul_rn(w, h);
                float denom = __fadd_rn(__fsub_rn(__fadd_rn(ar, jar), inter), 1e-9f);
                cond = __fdiv_rn(inter, denom) > 0.6f;   // exact ref order
            }
            if (cond) rows_ |= 1ULL << j;
        }
        // greedy scan (R13-verified): shfls independent of keepw -> pipelined
        unsigned long long keepw = (n == 64) ? ~0ULL : ((1ULL << n) - 1ULL);
        for (int i = 0; i < n; ++i) {
            unsigned long long ri = __shfl(rows_, i, 64);
            if ((keepw >> i) & 1ULL) keepw &= ~ri;
        }
        if (ln < n && ((keepw >> ln) & 1ULL))
            atomicOr(&keepbits[b * NCHUNK + (r >> 6)], 1ULL << (r & 63));
    } else if (n > 64) {
        // general path (n > 64): wave-local register-distributed keep bits.
        // Correctness-only; unreachable for this data distribution.
        unsigned long long membw = (ln < NCHUNK) ? U.c.lcm[c * NCHUNK + ln] : 0ULL;
        unsigned long long keepw2 = membw;
        for (int i = 0; i < K; ++i) {
            int ch = i >> 6;
            unsigned long long mw = __shfl(membw, ch, 64);
            unsigned long long kw = __shfl(keepw2, ch, 64);
            unsigned long long bi = 1ULL << (i & 63);
            if (!(mw & kw & bi)) continue;   // uniform (shfl results uniform)
            unsigned long long keyi = U.c.keys[i];             // uniform
            int idxi = (int)(~(unsigned)keyi);
            float4 bi4 = boxes4[(size_t)b * N + idxi];
            float bx1 = __fadd_rn(bi4.x, shf), by1 = __fadd_rn(bi4.y, shf);
            float bx2 = __fadd_rn(bi4.z, shf), by2 = __fadd_rn(bi4.w, shf);
            float ba = __fmul_rn(__fsub_rn(bx2, bx1), __fsub_rn(by2, by1));
            for (int c2 = ch; c2 < NCHUNK; ++c2) {
                int j = c2 * 64 + ln;
                unsigned long long mw2 = __shfl(membw, c2, 64);
                bool cond = false;
                if (j > i && ((mw2 >> ln) & 1ULL)) {
                    unsigned long long keyj = U.c.keys[j];
                    int idxj = (int)(~(unsigned)keyj);
                    float4 bj4 = boxes4[(size_t)b * N + idxj];
                    float x1 = __fadd_rn(bj4.x, shf), y1 = __fadd_rn(bj4.y, shf);
                    float x2 = __fadd_rn(bj4.z, shf), y2 = __fadd_rn(bj4.w, shf);
                    float arj = __fmul_rn(__fsub_rn(x2, x1), __fsub_rn(y2, y1));
                    float lx = fmaxf(bx1, x1), ly = fmaxf(by1, y1);
                    float rx = fminf(bx2, x2), ry = fminf(by2, y2);
                    float w = fmaxf(__fsub_rn(rx, lx), 0.0f);
                    float h = fmaxf(__fsub_rn(ry, ly), 0.0f);
                    float inter = __fmul_rn(w, h);
                    float denom = __fadd_rn(__fsub_rn(__fadd_rn(ba, arj), inter), 1e-9f);
                    cond = __fdiv_rn(inter, denom) > 0.6f;
                }
                unsigned long long sup = __ballot(cond);
                if (ln == c2) keepw2 &= ~sup;
            }
        }
        if (ln < NCHUNK && (keepw2 & membw))
            atomicOr(&keepbits[b * NCHUNK + ln], keepw2 & membw);
    }

    // ---- last-finisher detection + BLOCK-parallel output phase ----
    __threadfence();
    unsigned old = 0;
    if (ln == 0) old = atomicAdd(&done_ctr[b * CTR_STRIDE], 1u);
    old = (unsigned)__shfl((int)old, 0, 64);
    if (old == NC - 1) {
        // finisher wave: coherent kept read + per-chunk prefix into LDS
        __threadfence();
        unsigned long long kwv = 0ULL;
        if (ln < NCHUNK) kwv = atomicOr(&keepbits[b * NCHUNK + ln], 0ULL);
        unsigned pc = (unsigned)__popcll(kwv);
        unsigned incl = pc;
        #pragma unroll
        for (int o = 1; o < 32; o <<= 1) { unsigned u = __shfl_up(incl, o, 64); if (ln >= o) incl += u; }
        if (ln < NCHUNK) {
            U.c.kept[ln] = kwv;
            U.c.kcpref[ln] = incl - pc;      // exclusive kept prefix
        }
        if (ln == 31) U.c.total = (int)incl; // total kept
        if (ln == 0)  U.c.oflag = 1;
    }
    __syncthreads();

    if (U.c.oflag) {
        int total = U.c.total;
        float* dets  = out + (size_t)b * MAXDET * 6;
        float* flags = out + (size_t)B * MAXDET * 6 + (size_t)b * MAXDET;
        #pragma unroll
        for (int h = 0; h < 2; ++h) {
            int ch = wv * 2 + h;
            int i = ch * 64 + ln;
            unsigned long long m = U.c.kept[ch];
            bool k = ((m >> ln) & 1ULL) != 0ULL;
            int kp = (int)U.c.kcpref[ch];
            int np = ch * 64 - kp;           // exclusive non-kept prefix
            int slot = k ? (kp + (int)__popcll(m & below))
                         : (total + np + (int)__popcll((~m) & below));
            if (slot < MAXDET) {
                unsigned long long key = U.c.keys[i];
                float s, ox1, oy1, ox2, oy2; int oc;
                if (key == 0ULL) {
                    s = -1.0f; ox1 = oy1 = ox2 = oy2 = 0.0f; oc = 0;
                } else {
                    s = __uint_as_float((unsigned)(key >> 32));
                    int idx = (int)(~(unsigned)key);
                    float4 bb = boxes4[(size_t)b * N + idx];
                    ox1 = bb.x; oy1 = bb.y; ox2 = bb.z; oy2 = bb.w;
                    oc = cls_id[b * N + idx];
                }
                dets[slot * 6 + 0] = ox1;
                dets[slot * 6 + 1] = oy1;
                dets[slot * 6 + 2] = ox2;
                dets[slot * 6 + 3] = oy2;
                dets[slot * 6 + 4] = s;
                dets[slot * 6 + 5] = (float)oc;
                flags[slot] = k ? 1.0f : 0.0f;
            }
        }
    }
}

// ---------------------------------------------------------------------------
extern "C" void kernel_launch(void* const* d_in, const int* in_sizes, int n_in,
                              void* d_out, int out_size, void* d_ws, size_t ws_size,
                              hipStream_t stream) {
    const float* x = (const float*)d_in[0];
    float* out = (float*)d_out;

    char* ws = (char*)d_ws;
    size_t off = 0;
    auto alloc = [&](size_t bytes) -> void* {
        void* p = ws + off;
        off += bytes;
        off = (off + 255) & ~(size_t)255;
        return p;
    };

    float*    scores = (float*)    alloc((size_t)B * N * 4);
    int*      cls_id = (int*)      alloc((size_t)B * N * 4);
    float4*   boxes4 = (float4*)   alloc((size_t)B * N * 16);
    unsigned long long* keepbits = (unsigned long long*) alloc((size_t)B * NCHUNK * 8);
    unsigned* done_ctr = (unsigned*) alloc((size_t)B * CTR_STRIDE * 4);
    (void)ws_size; // needs ~2.6 MB

    nms_score_kernel<<<dim3((N + STILE - 1) / STILE, B), 256, 0, stream>>>(
        x, scores, cls_id, boxes4, done_ctr, keepbits);
    nms_tail_kernel<<<5 * B, 1024, 0, stream>>>(
        scores, boxes4, cls_id, keepbits, done_ctr, out);
}

// Round 17
// 132.145 us; speedup vs baseline: 1.3438x; 1.0044x over previous
//
#include <hip/hip_runtime.h>

#define B 8
#define N 25200
#define ROW 85
#define NC 80
#define K 2048
#define MAXDET 300
#define NBUCKET 4096
#define CAND_CAP 4096
#define NCHUNK 32   /* K/64 */
#define STILE 64    /* score tile rows */
#define CTR_STRIDE 64   /* u32 stride per batch counter: 256B, no false sharing */

// ---------------------------------------------------------------------------
// Kernel 1: score/cls per box + xyxy boxes4 (bit-identical box math).
// Block (0,b) also zeroes done counter and keepbits for kernel 2.
// ---------------------------------------------------------------------------
__global__ void __launch_bounds__(256)
nms_score_kernel(const float* __restrict__ x,
                 float* __restrict__ scores,
                 int* __restrict__ cls_id,
                 float4* __restrict__ boxes4,
                 unsigned* __restrict__ done_ctr,
                 unsigned long long* __restrict__ keepbits) {
    int b = blockIdx.y;
    int i0 = blockIdx.x * STILE;
    if (blockIdx.x == 0) {
        if (threadIdx.x == 0) done_ctr[b * CTR_STRIDE] = 0u;
        if (threadIdx.x < NCHUNK) keepbits[b * NCHUNK + threadIdx.x] = 0ULL;
    }
    int rows = N - i0; if (rows > STILE) rows = STILE;
    __shared__ float lx[STILE * ROW];   // 21760 B
    {
        const float4* s4 = (const float4*)(x + ((size_t)b * N + i0) * ROW);
        float4* d4 = (float4*)lx;
        int nv = rows * ROW / 4;        // 1360 or 1020 (both exact)
        for (int k = threadIdx.x; k < nv; k += 256) d4[k] = s4[k];
    }
    __syncthreads();
    int g = threadIdx.x >> 2;          // box in tile
    int q = threadIdx.x & 3;
    if (g >= rows) return;             // uniform across the 4-lane group
    const float* p = lx + g * ROW;
    float obj = p[4];
    float best = -1e30f;
    int bc = 127;
    if (obj > 0.3f) {
        #pragma unroll
        for (int k = 0; k < 20; ++k) {
            int c = q + 4 * k;
            float v = __fmul_rn(p[5 + c], obj);   // exact, no FMA
            if (v > best) { best = v; bc = c; }   // strict >: in-lane first-max
        }
    }
    #pragma unroll
    for (int m = 1; m < 4; m <<= 1) {   // combine: higher v, tie -> smaller class
        float ov = __shfl_xor(best, m, 64);
        int   oc = __shfl_xor(bc, m, 64);
        if (ov > best || (ov == best && oc < bc)) { best = ov; bc = oc; }
    }
    if (q == 0) {
        int i = i0 + g;
        float score = (obj > 0.3f && best > 0.3f) ? best : -1.0f;
        scores[b * N + i] = score;
        cls_id[b * N + i] = (bc == 127) ? 0 : bc;
        float cx = p[0], cy = p[1], w = p[2], h = p[3];
        float hx = __fmul_rn(w, 0.5f);
        float hy = __fmul_rn(h, 0.5f);
        boxes4[b * N + i] = make_float4(__fsub_rn(cx, hx), __fsub_rn(cy, hy),
                                        __fadd_rn(cx, hx), __fadd_rn(cy, hy));
    }
}

// ---------------------------------------------------------------------------
// Kernel 2 (tail): 40 blocks x 1024 threads (R16 champion chassis).
// R17 changes (both scheduling-only, fp/sets/order untouched):
//  1. XCD-aware batch mapping: b = bid % 8 (not bid/5) so all 5 replicas of
//     a batch land on the SAME XCD under round-robin dispatch -> one L2
//     fetch of the 100KB score row serves all 5 (R16 FETCH=5MB was the 5
//     replicas each far-fetching from different XCDs' L2s).
//  2. Early-issue score loads: the 7 float4 loads are issued BEFORE the
//     24KB LDS zeroing so HBM/LLC latency hides under the zero+barrier.
// ---------------------------------------------------------------------------
__global__ void __launch_bounds__(1024, 1)
nms_tail_kernel(const float* __restrict__ scores,
                const float4* __restrict__ boxes4,
                const int* __restrict__ cls_id,
                unsigned long long* __restrict__ keepbits,
                unsigned* __restrict__ done_ctr,
                float* __restrict__ out) {
    __shared__ union {
        struct {   // SELECT phase: 56 KB
            unsigned loff[NBUCKET];              // 16 KB hist -> start ranks
            unsigned lcnt16[NBUCKET / 2];        // 8 KB packed u16 cursors
            unsigned long long lk[CAND_CAP];     // 32 KB sort keys @ byte 24K
        } s;
        struct {   // NMS phase: ~54 KB
            unsigned long long keys[K];          // 16 KB sorted keys @ byte 0
            unsigned long long lcm[NC * NCHUNK]; // 20 KB class masks @ 16K
            float4 wbox[16][64];                 // 16 KB per-wave staged boxes
            unsigned long long kept[NCHUNK];     // finisher: kept words
            unsigned kcpref[NCHUNK];             // finisher: kept prefix
            int total;                           // finisher: total kept
            int oflag;                           // finisher-block flag
        } c;
    } U;
    __shared__ unsigned wsum[16];

    int bid = blockIdx.x;
    int t = threadIdx.x;
    int ln = t & 63, wv = t >> 6;
    unsigned long long below = (ln == 0) ? 0ULL : (~0ULL >> (64 - ln));

    int b = bid % 8;            // XCD-aware: batch b's 5 blocks share an XCD
    int grp = bid / 8;          // 0..4
    int c = grp * 16 + wv;      // this wave's class, 0..79
    constexpr int NV4 = N / 4;                    // 6300, exact
    constexpr int NITER4 = (NV4 + 1023) / 1024;   // 7

    // ================= SELECT phase (replicated per block) =================
    // early-issue the score loads (latency hides under the LDS zeroing)
    const float4* sc4 = (const float4*)(scores + (size_t)b * N);
    float4 sreg4[NITER4];
    #pragma unroll
    for (int r = 0; r < NITER4; ++r) {
        int i4 = t + r * 1024;
        sreg4[r] = (i4 < NV4) ? sc4[i4] : make_float4(-1.f, -1.f, -1.f, -1.f);
    }
    {   // zero histogram + cursors (24 KB)
        uint4 z = {0u, 0u, 0u, 0u};
        uint4* d1 = (uint4*)U.s.loff;
        for (int k = t; k < (NBUCKET + NBUCKET / 2) / 4; k += 1024) d1[k] = z;
    }
    for (int k = t; k < CAND_CAP; k += 1024) U.s.lk[k] = 0ULL;
    __syncthreads();

    // histogram pass from register-cached scores
    #pragma unroll
    for (int r = 0; r < NITER4; ++r) {
        float4 v = sreg4[r];
        float sv[4] = {v.x, v.y, v.z, v.w};
        #pragma unroll
        for (int k = 0; k < 4; ++k) {
            float s = sv[k];
            if (s > 0.0f) {
                int q = (int)(__fmul_rn(s, 4096.0f));
                if (q > NBUCKET - 1) q = NBUCKET - 1;
                atomicAdd(&U.s.loff[q], 1u);
            }
        }
    }
    __syncthreads();

    // descending exclusive scan in place: loff[q] = count in buckets > q.
    // thread t owns buckets 4095-4t .. 4092-4t (uint4 index 1023-t).
    {
        unsigned v[4];
        unsigned A4 = (unsigned)(NBUCKET / 4 - 1 - t);
        {
            uint4 u0 = ((uint4*)U.s.loff)[A4];
            v[0] = u0.w; v[1] = u0.z; v[2] = u0.y; v[3] = u0.x;
        }
        unsigned S = v[0] + v[1] + v[2] + v[3];
        unsigned pref = S;
        #pragma unroll
        for (int o = 1; o < 64; o <<= 1) { unsigned u = __shfl_up(pref, o, 64); if (ln >= o) pref += u; }
        if (ln == 63) wsum[wv] = pref;
        __syncthreads();
        unsigned wbase = 0;
        for (int w = 0; w < wv; ++w) wbase += wsum[w];
        unsigned running = wbase + pref - S;
        unsigned o[4];
        #pragma unroll
        for (int k = 0; k < 4; ++k) { o[3 - k] = running; running += v[k]; }
        ((uint4*)U.s.loff)[A4] = make_uint4(o[0], o[1], o[2], o[3]);
    }
    __syncthreads();

    // placement (counting sort) from register-cached scores
    #pragma unroll
    for (int r = 0; r < NITER4; ++r) {
        int i4 = t + r * 1024;
        float4 v = sreg4[r];
        float sv[4] = {v.x, v.y, v.z, v.w};
        #pragma unroll
        for (int k = 0; k < 4; ++k) {
            float s = sv[k];
            if (s > 0.0f) {
                int i = i4 * 4 + k;
                int q = (int)(__fmul_rn(s, 4096.0f));
                if (q > NBUCKET - 1) q = NBUCKET - 1;
                unsigned start = U.s.loff[q];
                if (start < CAND_CAP) {
                    unsigned sh = (q & 1) * 16;
                    unsigned old = atomicAdd(&U.s.lcnt16[q >> 1], 1u << sh);
                    unsigned rank = (old >> sh) & 0xFFFFu;
                    unsigned pos = start + rank;
                    if (pos < CAND_CAP) {
                        unsigned long long key =
                            ((unsigned long long)__float_as_uint(s) << 32) | (unsigned)(~i);
                        U.s.lk[pos] = key;
                    }
                }
            }
        }
    }
    __syncthreads();

    // per-bucket insertion sort (descending keys), disjoint ranges
    for (int q = t; q < NBUCKET; q += 1024) {
        unsigned start = U.s.loff[q];
        if (start < CAND_CAP) {
            unsigned cc = (U.s.lcnt16[q >> 1] >> ((q & 1) * 16)) & 0xFFFFu;
            unsigned m = cc;
            if (m > CAND_CAP - start) m = CAND_CAP - start;
            if (m >= 2) {
                for (unsigned a = start + 1; a < start + m; ++a) {
                    unsigned long long kv = U.s.lk[a];
                    unsigned p2 = a;
                    while (p2 > start && U.s.lk[p2 - 1] < kv) { U.s.lk[p2] = U.s.lk[p2 - 1]; --p2; }
                    U.s.lk[p2] = kv;
                }
            }
        }
    }
    __syncthreads();

    // ================= transition: keys <- lk (disjoint LDS regions) =======
    // keys @ bytes [0,16K) ; lk @ bytes [24K,56K) -> safe concurrent copy.
    for (int r = t; r < K; r += 1024) U.c.keys[r] = U.s.lk[r];
    __syncthreads();
    // lcm overlaps dead lcnt16/lk only after the copy barrier.
    for (int k = t; k < NC * NCHUNK; k += 1024) U.c.lcm[k] = 0ULL;
    if (t == 0) U.c.oflag = 0;
    __syncthreads();

    // parallel class-mask build (1024 threads x 2 ranks)
    for (int r = t; r < K; r += 1024) {
        unsigned long long key = U.c.keys[r];
        if (key != 0ULL) {
            int idx = (int)(~(unsigned)key);
            int cc = cls_id[b * N + idx];
            atomicOr(&U.c.lcm[cc * NCHUNK + (r >> 6)], 1ULL << (r & 63));
        }
    }
    __syncthreads();

    // ================= per-wave class NMS (one round) =================
    // register compaction from LDS masks: lane ln -> ln-th member of class c
    int n = 0, r = -1, ch_i = -1, myk = -1;
    unsigned long long mych = 0ULL;
    for (int ch = 0; ch < NCHUNK; ++ch) {
        unsigned long long m = U.c.lcm[c * NCHUNK + ch];   // LDS, wave-uniform
        int cnt = __popcll(m);
        if (myk < 0 && ln < n + cnt) { mych = m; myk = ln - n; ch_i = ch; }
        n += cnt;
    }
    if (myk >= 0) {
        unsigned long long mm = mych;
        for (int z = 0; z < myk; ++z) mm &= mm - 1;
        r = ch_i * 64 + (int)__builtin_ctzll(mm);
    }

    float shf = __fmul_rn((float)c, 4096.0f);   // class shift (uniform)

    if (n > 0 && n <= 64) {
        // fast path: member ln computes its shifted box in-lane from boxes4,
        // stages it to the per-wave LDS array (one ds_write).
        float x1 = 0.f, y1 = 0.f, x2 = 0.f, y2 = 0.f, ar = 0.f;
        if (ln < n) {
            unsigned long long key = U.c.keys[r];
            int idx = (int)(~(unsigned)key);
            float4 bb = boxes4[(size_t)b * N + idx];
            x1 = __fadd_rn(bb.x, shf); y1 = __fadd_rn(bb.y, shf);
            x2 = __fadd_rn(bb.z, shf); y2 = __fadd_rn(bb.w, shf);
            ar = __fmul_rn(__fsub_rn(x2, x1), __fsub_rn(y2, y1));
            U.c.wbox[wv][ln] = make_float4(x1, y1, x2, y2);
        }
        // row build: lane ln = suppressor i; box_j via broadcast LDS read
        // (j-area recomputed with the identical op sequence -> bit-identical).
        unsigned long long rows_ = 0ULL;
        for (int j = 0; j < n; ++j) {
            float4 jb = U.c.wbox[wv][j];         // wave-uniform broadcast
            bool cond = false;
            if (ln < n && j > ln) {
                float jar = __fmul_rn(__fsub_rn(jb.z, jb.x), __fsub_rn(jb.w, jb.y));
                float lx = fmaxf(x1, jb.x), ly = fmaxf(y1, jb.y);
                float rx = fminf(x2, jb.z), ry = fminf(y2, jb.w);
                float w = fmaxf(__fsub_rn(rx, lx), 0.0f);
                float h = fmaxf(__fsub_rn(ry, ly), 0.0f);
                float inter = __fmul_rn(w, h);
                float denom = __fadd_rn(__fsub_rn(__fadd_rn(ar, jar), inter), 1e-9f);
                cond = __fdiv_rn(inter, denom) > 0.6f;   // exact ref order
            }
            if (cond) rows_ |= 1ULL << j;
        }
        // greedy scan (R13-verified): shfls independent of keepw -> pipelined
        unsigned long long keepw = (n == 64) ? ~0ULL : ((1ULL << n) - 1ULL);
        for (int i = 0; i < n; ++i) {
            unsigned long long ri = __shfl(rows_, i, 64);
            if ((keepw >> i) & 1ULL) keepw &= ~ri;
        }
        if (ln < n && ((keepw >> ln) & 1ULL))
            atomicOr(&keepbits[b * NCHUNK + (r >> 6)], 1ULL << (r & 63));
    } else if (n > 64) {
        // general path (n > 64): wave-local register-distributed keep bits.
        // Correctness-only; unreachable for this data distribution.
        unsigned long long membw = (ln < NCHUNK) ? U.c.lcm[c * NCHUNK + ln] : 0ULL;
        unsigned long long keepw2 = membw;
        for (int i = 0; i < K; ++i) {
            int ch = i >> 6;
            unsigned long long mw = __shfl(membw, ch, 64);
            unsigned long long kw = __shfl(keepw2, ch, 64);
            unsigned long long bi = 1ULL << (i & 63);
            if (!(mw & kw & bi)) continue;   // uniform (shfl results uniform)
            unsigned long long keyi = U.c.keys[i];             // uniform
            int idxi = (int)(~(unsigned)keyi);
            float4 bi4 = boxes4[(size_t)b * N + idxi];
            float bx1 = __fadd_rn(bi4.x, shf), by1 = __fadd_rn(bi4.y, shf);
            float bx2 = __fadd_rn(bi4.z, shf), by2 = __fadd_rn(bi4.w, shf);
            float ba = __fmul_rn(__fsub_rn(bx2, bx1), __fsub_rn(by2, by1));
            for (int c2 = ch; c2 < NCHUNK; ++c2) {
                int j = c2 * 64 + ln;
                unsigned long long mw2 = __shfl(membw, c2, 64);
                bool cond = false;
                if (j > i && ((mw2 >> ln) & 1ULL)) {
                    unsigned long long keyj = U.c.keys[j];
                    int idxj = (int)(~(unsigned)keyj);
                    float4 bj4 = boxes4[(size_t)b * N + idxj];
                    float x1 = __fadd_rn(bj4.x, shf), y1 = __fadd_rn(bj4.y, shf);
                    float x2 = __fadd_rn(bj4.z, shf), y2 = __fadd_rn(bj4.w, shf);
                    float arj = __fmul_rn(__fsub_rn(x2, x1), __fsub_rn(y2, y1));
                    float lx = fmaxf(bx1, x1), ly = fmaxf(by1, y1);
                    float rx = fminf(bx2, x2), ry = fminf(by2, y2);
                    float w = fmaxf(__fsub_rn(rx, lx), 0.0f);
                    float h = fmaxf(__fsub_rn(ry, ly), 0.0f);
                    float inter = __fmul_rn(w, h);
                    float denom = __fadd_rn(__fsub_rn(__fadd_rn(ba, arj), inter), 1e-9f);
                    cond = __fdiv_rn(inter, denom) > 0.6f;
                }
                unsigned long long sup = __ballot(cond);
                if (ln == c2) keepw2 &= ~sup;
            }
        }
        if (ln < NCHUNK && (keepw2 & membw))
            atomicOr(&keepbits[b * NCHUNK + ln], keepw2 & membw);
    }

    // ---- last-finisher detection + BLOCK-parallel output phase ----
    __threadfence();
    unsigned old = 0;
    if (ln == 0) old = atomicAdd(&done_ctr[b * CTR_STRIDE], 1u);
    old = (unsigned)__shfl((int)old, 0, 64);
    if (old == NC - 1) {
        // finisher wave: coherent kept read + per-chunk prefix into LDS
        __threadfence();
        unsigned long long kwv = 0ULL;
        if (ln < NCHUNK) kwv = atomicOr(&keepbits[b * NCHUNK + ln], 0ULL);
        unsigned pc = (unsigned)__popcll(kwv);
        unsigned incl = pc;
        #pragma unroll
        for (int o = 1; o < 32; o <<= 1) { unsigned u = __shfl_up(incl, o, 64); if (ln >= o) incl += u; }
        if (ln < NCHUNK) {
            U.c.kept[ln] = kwv;
            U.c.kcpref[ln] = incl - pc;      // exclusive kept prefix
        }
        if (ln == 31) U.c.total = (int)incl; // total kept
        if (ln == 0)  U.c.oflag = 1;
    }
    __syncthreads();

    if (U.c.oflag) {
        int total = U.c.total;
        float* dets  = out + (size_t)b * MAXDET * 6;
        float* flags = out + (size_t)B * MAXDET * 6 + (size_t)b * MAXDET;
        #pragma unroll
        for (int h = 0; h < 2; ++h) {
            int ch = wv * 2 + h;
            int i = ch * 64 + ln;
            unsigned long long m = U.c.kept[ch];
            bool k = ((m >> ln) & 1ULL) != 0ULL;
            int kp = (int)U.c.kcpref[ch];
            int np = ch * 64 - kp;           // exclusive non-kept prefix
            int slot = k ? (kp + (int)__popcll(m & below))
                         : (total + np + (int)__popcll((~m) & below));
            if (slot < MAXDET) {
                unsigned long long key = U.c.keys[i];
                float s, ox1, oy1, ox2, oy2; int oc;
                if (key == 0ULL) {
                    s = -1.0f; ox1 = oy1 = ox2 = oy2 = 0.0f; oc = 0;
                } else {
                    s = __uint_as_float((unsigned)(key >> 32));
                    int idx = (int)(~(unsigned)key);
                    float4 bb = boxes4[(size_t)b * N + idx];
                    ox1 = bb.x; oy1 = bb.y; ox2 = bb.z; oy2 = bb.w;
                    oc = cls_id[b * N + idx];
                }
                dets[slot * 6 + 0] = ox1;
                dets[slot * 6 + 1] = oy1;
                dets[slot * 6 + 2] = ox2;
                dets[slot * 6 + 3] = oy2;
                dets[slot * 6 + 4] = s;
                dets[slot * 6 + 5] = (float)oc;
                flags[slot] = k ? 1.0f : 0.0f;
            }
        }
    }
}

// ---------------------------------------------------------------------------
extern "C" void kernel_launch(void* const* d_in, const int* in_sizes, int n_in,
                              void* d_out, int out_size, void* d_ws, size_t ws_size,
                              hipStream_t stream) {
    const float* x = (const float*)d_in[0];
    float* out = (float*)d_out;

    char* ws = (char*)d_ws;
    size_t off = 0;
    auto alloc = [&](size_t bytes) -> void* {
        void* p = ws + off;
        off += bytes;
        off = (off + 255) & ~(size_t)255;
        return p;
    };

    float*    scores = (float*)    alloc((size_t)B * N * 4);
    int*      cls_id = (int*)      alloc((size_t)B * N * 4);
    float4*   boxes4 = (float4*)   alloc((size_t)B * N * 16);
    unsigned long long* keepbits = (unsigned long long*) alloc((size_t)B * NCHUNK * 8);
    unsigned* done_ctr = (unsigned*) alloc((size_t)B * CTR_STRIDE * 4);
    (void)ws_size; // needs ~2.6 MB

    nms_score_kernel<<<dim3((N + STILE - 1) / STILE, B), 256, 0, stream>>>(
        x, scores, cls_id, boxes4, done_ctr, keepbits);
    nms_tail_kernel<<<5 * B, 1024, 0, stream>>>(
        scores, boxes4, cls_id, keepbits, done_ctr, out);
}